// Round 5
// baseline (312.099 us; speedup 1.0000x reference)
//
#include <hip/hip_runtime.h>

#define NB 256   // batch
#define NS 256   // seq len == number of steps
#define NE 2     // encoder dim
#define ND 128   // decoder dim
#define NT 512   // threads per block (8 waves)
#define NN 16    // Chebyshev nodes/degree for the h -> context map

typedef float vf4 __attribute__((ext_vector_type(4)));
typedef _Float16 f16x8 __attribute__((ext_vector_type(8)));
typedef _Float16 f16x2 __attribute__((ext_vector_type(2)));
typedef float f32x4 __attribute__((ext_vector_type(4)));

constexpr float L2E = 1.4426950408889634f;  // log2(e)
constexpr float PI_F = 3.14159265358979323846f;

// Monomial coefficients of Chebyshev T_k: T_k(h) = sum_m CT[k][m] h^m (exact ints).
__device__ const float CT[16][16] = {
 {1,0,0,0,0,0,0,0,0,0,0,0,0,0,0,0},
 {0,1,0,0,0,0,0,0,0,0,0,0,0,0,0,0},
 {-1,0,2,0,0,0,0,0,0,0,0,0,0,0,0,0},
 {0,-3,0,4,0,0,0,0,0,0,0,0,0,0,0,0},
 {1,0,-8,0,8,0,0,0,0,0,0,0,0,0,0,0},
 {0,5,0,-20,0,16,0,0,0,0,0,0,0,0,0,0},
 {-1,0,18,0,-48,0,32,0,0,0,0,0,0,0,0,0},
 {0,-7,0,56,0,-112,0,64,0,0,0,0,0,0,0,0},
 {1,0,-32,0,160,0,-256,0,128,0,0,0,0,0,0,0},
 {0,9,0,-120,0,432,0,-576,0,256,0,0,0,0,0},
 {-1,0,50,0,-400,0,1120,0,-1280,0,512,0,0,0,0,0},
 {0,-11,0,220,0,-1232,0,2816,0,-2816,0,1024,0,0,0,0},
 {1,0,-72,0,840,0,-3584,0,6912,0,-6144,0,2048,0,0,0},
 {0,13,0,-364,0,2912,0,-9984,0,16640,0,-13312,0,4096,0,0},
 {-1,0,98,0,-1568,0,9408,0,-26880,0,39424,0,-28672,0,8192,0},
 {0,-15,0,560,0,-6048,0,28800,0,-70400,0,92160,0,-61440,0,16384}};

// DPP add: x + dpp_move(x). All-VALU cross-lane (no LDS pipe, no lgkmcnt).
template <int C>
__device__ __forceinline__ float dppadd(float x) {
    return x + __builtin_bit_cast(float,
        __builtin_amdgcn_update_dpp(0, __builtin_bit_cast(int, x), C, 0xF, 0xF, true));
}
__device__ __forceinline__ float red_wave64(float x) {    // valid in lane 63
    x = dppadd<0xB1>(x); x = dppadd<0x4E>(x); x = dppadd<0x141>(x);
    x = dppadd<0x140>(x); x = dppadd<0x142>(x); x = dppadd<0x143>(x); return x;
}
__device__ __forceinline__ float red_half32(float x) {    // 32-lane sums
    x = dppadd<0xB1>(x); x = dppadd<0x4E>(x); x = dppadd<0x141>(x);
    x = dppadd<0x140>(x); x = dppadd<0x142>(x); return x;
}
// All-lane 16-sum via mirror stages (each is a permutation => valid everywhere).
__device__ __forceinline__ float red16_all(float x) {
    x = dppadd<0xB1>(x);   // xor1 (quad perm)
    x = dppadd<0x4E>(x);   // xor2 (quad perm)
    x = dppadd<0x141>(x);  // xor4 (row half mirror)
    x = dppadd<0x140>(x);  // xor8 (row mirror)
    return x;
}

// One block per batch element; 256-step recurrence in-block, ONE barrier/step.
// Attention collapsed (setup) to a degree-15 monomial poly G per channel.
// Gate matvec on the MFMA pipe, wave-local B tiling (round-3 mapping): all 4
// gates of this thread's g land in acc[rt][0] with zero cross-lane traffic.
// The context scalar x(k) = sum_g G(h_g(k-1)) is computed by EVERY WAVE
// AUTONOMOUSLY at the step TOP from the f16 h buffer (each lane evaluates
// the full poly at its own 2-h pair, then an all-lane butterfly: 4 DPP
// mirrors + 2 ds_bpermute crossings). This runs in the shadow of the af
// ds_read latency and in parallel with the MFMA chain, and DELETES the old
// writer-side tail (phaseG poly + 6 serial DPP + xwbuf write) from the
// critical path. Tail is now just: h -> cvt -> one ds_write_b16 -> barrier.
__global__ __launch_bounds__(NT, 2)
void attn_lstm_decoder(const float* __restrict__ enc,   // [B,S,E]
                       const float* __restrict__ W1w,   // [S,S]
                       const float* __restrict__ W1b,   // [S]
                       const float* __restrict__ W2w,   // [S,2S]
                       const float* __restrict__ W2b,   // [S]
                       const float* __restrict__ Wih,   // [4D,E]
                       const float* __restrict__ Whh,   // [4D,D]
                       const float* __restrict__ bih,   // [4D]
                       const float* __restrict__ bhh,   // [4D]
                       float* __restrict__ out)         // [S,B,D]
{
    const int b    = blockIdx.x;
    const int t    = threadIdx.x;
    const int wave = t >> 6;
    const int lane = t & 63;
    const int grp  = lane >> 4;       // MFMA k-group / copy idx
    const int nib  = lane & 15;       // MFMA n-index == g within the wave
    const int gl   = 16 * wave + nib; // this thread's decoder dim index
    // setup-only:
    const int half = lane >> 5;
    const int idx  = lane & 31;
    const int jnode = 2 * wave + half;

    __shared__ __align__(16) _Float16 hist16[2 * ND];   // f16 h double buffer
    __shared__ float A2_l[NS];
    __shared__ float g2_l[NS];
    __shared__ float e0_l[NS];
    __shared__ float e1_l[NS];
    __shared__ float Ml[NN * NN];
    __shared__ float2 Pn[NN];
    __shared__ float2 Vl[NN];
    __shared__ float Pm0[NN], Pm1[NN];

    // ---------------- setup (once per block) ----------------
    {
        float v = enc[b * (NS * NE) + t];      // coalesced
        if (t & 1) e1_l[t >> 1] = v; else e0_l[t >> 1] = v;
    }
    if (t < NN * NN) {
        const int mi = t >> 4, mj = t & 15;
        const float w = (mi == 0) ? (1.0f / NN) : (2.0f / NN);
        Ml[t] = w * __cosf((float)(mi * (2 * mj + 1)) * (PI_F / (2 * NN)));
    }
    __syncthreads();

    // w1sum rows and w2term rows: 32 rows per wave (DPP reductions).
    for (int r = 0; r < 32; ++r) {
        const int s = wave * 32 + r;
        float p = W1w[s * NS + lane]       + W1w[s * NS + lane + 64]
                + W1w[s * NS + lane + 128] + W1w[s * NS + lane + 192];
        p = red_wave64(p);
        if (lane == 63) g2_l[s] = p * (2.0f * L2E);
        float qq = 0.0f;
        #pragma unroll
        for (int kk = 0; kk < 8; ++kk) {
            const int c = lane + kk * 64;
            const float ev = (c & 1) ? e1_l[c >> 1] : e0_l[c >> 1];
            qq = fmaf(ev, W2w[s * (2 * NS) + c], qq);
        }
        qq = red_wave64(qq);
        if (lane == 63) A2_l[s] = (qq + W2b[s] + W1b[s]) * (2.0f * L2E);
    }
    __syncthreads();

    // One-time node softmax: F(y_j) for the 16 Chebyshev nodes (2 nodes/wave).
    {
        const float y  = __cosf((float)(2 * jnode + 1) * (PI_F / (2 * NN)));
        const float C2 = -2.0f * L2E;
        float l = 0.0f, p0 = 0.0f, p1 = 0.0f;
        #pragma unroll
        for (int k = 0; k < 8; ++k) {
            const int s = k * 32 + idx;
            const float m1 = fmaf(y, g2_l[s], A2_l[s]);
            const float u  = __builtin_amdgcn_exp2f(m1);
            const float rc = __builtin_amdgcn_rcpf(u + 1.0f);
            const float e  = __builtin_amdgcn_exp2f(rc * C2);
            l += e;
            p0 = fmaf(e, e0_l[s], p0);
            p1 = fmaf(e, e1_l[s], p1);
        }
        l = red_half32(l); p0 = red_half32(p0); p1 = red_half32(p1);
        if ((lane & 31) == 31) {
            const float rl = __builtin_amdgcn_rcpf(l);
            Pn[jnode] = make_float2(p0 * rl, p1 * rl);
        }
    }
    __syncthreads();

    // DCT collapse: V[i] = sum_j M[i][j]*Pn[j], 1/ND folded in.
    if (t < NN) {
        float v0 = 0.0f, v1 = 0.0f;
        #pragma unroll
        for (int j = 0; j < NN; ++j) {
            v0 = fmaf(Ml[t * NN + j], Pn[j].x, v0);
            v1 = fmaf(Ml[t * NN + j], Pn[j].y, v1);
        }
        Vl[t] = make_float2(v0 * (1.0f / ND), v1 * (1.0f / ND));
    }

    // W_hh MFMA B-fragments, WAVE-LOCAL rows: tile rt (= gate index) covers
    // rows 128*rt + 16*wave + [0,16). Lane holds B[k][n]: n = nib,
    // k = 32*kt + 8*grp + e (contiguous 8, packed little-endian).
    f16x8 wf[4][4];
    #pragma unroll
    for (int rt = 0; rt < 4; ++rt) {
        const int row = 128 * rt + 16 * wave + nib;
        #pragma unroll
        for (int kt = 0; kt < 4; ++kt) {
            const vf4 wa = *reinterpret_cast<const vf4*>(Whh + row * ND + 32 * kt + 8 * grp);
            const vf4 wb = *reinterpret_cast<const vf4*>(Whh + row * ND + 32 * kt + 8 * grp + 4);
            f16x8 wv;
            wv[0] = (_Float16)wa.x; wv[1] = (_Float16)wa.y;
            wv[2] = (_Float16)wa.z; wv[3] = (_Float16)wa.w;
            wv[4] = (_Float16)wb.x; wv[5] = (_Float16)wb.y;
            wv[6] = (_Float16)wb.z; wv[7] = (_Float16)wb.w;
            wf[rt][kt] = wv;
        }
    }
    // All-4-gate per-lane constants for this thread's g (rows 128*j + gl).
    float wi0_[4], wi1_[4], bb_[4];
    #pragma unroll
    for (int j = 0; j < 4; ++j) {
        const int r = 128 * j + gl;
        wi0_[j] = Wih[r * 2 + 0];
        wi1_[j] = Wih[r * 2 + 1];
        bb_[j]  = bih[r] + bhh[r];
    }

    // zero-init h buffer slot 1 (input of step 0)
    if (t < ND) hist16[ND + t] = (_Float16)0.0f;
    float h_reg = 0.0f, c_reg = 0.0f;
    __syncthreads();                   // Vl visible

    // Chebyshev -> monomial: Pm[m] = sum_k V[k] * CT[k][m].
    if (t < NN) {
        float s0 = 0.0f, s1 = 0.0f;
        #pragma unroll
        for (int k = 0; k < NN; ++k) {
            s0 = fmaf(Vl[k].x, CT[k][t], s0);
            s1 = fmaf(Vl[k].y, CT[k][t], s1);
        }
        Pm0[t] = s0; Pm1[t] = s1;
    }
    __syncthreads();                   // Pm visible

    // Full monomial coefficient sets in registers (broadcast LDS reads,
    // setup-only; every index below is compile-time after unrolling).
    float C0[16], C1[16];
    #pragma unroll
    for (int i = 0; i < 16; ++i) { C0[i] = Pm0[i]; C1[i] = Pm1[i]; }

    // Even/odd Horner: G(h) = E(h^2) + h*O(h^2), E/O degree-7.
    auto evalG = [&](float h, const float (&C)[16]) -> float {
        const float h2 = h * h;
        float e = C[14], o = C[15];
        #pragma unroll
        for (int k = 12; k >= 0; k -= 2) {
            e = fmaf(e, h2, C[k]);
            o = fmaf(o, h2, C[k + 1]);
        }
        return fmaf(h, o, e);
    };

    // This lane's h-pair for the x-evaluation: bijection (grp,nib) -> pair.
    // kt = nib>>2, p = nib&3 : j0 = 32*kt + 8*grp + 2*p  (j0, j0+1).
    const int jpair = 32 * (nib >> 2) + 8 * grp + 2 * (nib & 3);
    // bpermute byte indices for the xor16 / xor32 butterfly crossings.
    const int idx16 = ((lane ^ 16) << 2);
    const int idx32 = ((lane ^ 32) << 2);

    // ---------------- the recurrence (ONE barrier per step) ----------------
    for (int step = 0; step < NS; ++step) {
        const int rs = (step & 1) ^ 1;   // buffer holding h(step-1)
        const int ws = step & 1;         // buffer for h(step)
        const _Float16* hb = &hist16[rs * ND];

        // A fragments: each 16-lane group reads the SAME 16B of h (broadcast),
        // so A[m][k] = h[k] for every m; all C rows are identical.
        const f16x8 af0 = __builtin_bit_cast(f16x8, *reinterpret_cast<const int4*>(hb + 0  + 8 * grp));
        const f16x8 af1 = __builtin_bit_cast(f16x8, *reinterpret_cast<const int4*>(hb + 32 + 8 * grp));
        const f16x8 af2 = __builtin_bit_cast(f16x8, *reinterpret_cast<const int4*>(hb + 64 + 8 * grp));
        const f16x8 af3 = __builtin_bit_cast(f16x8, *reinterpret_cast<const int4*>(hb + 96 + 8 * grp));
        // This lane's own h-pair (4B read; <=2 lanes/bank => conflict-free).
        const f16x2 hp2 = *reinterpret_cast<const f16x2*>(hb + jpair);

        // ---- x(step) computed wave-locally, hidden under af latency ----
        const float ha = (float)hp2[0];
        const float hc = (float)hp2[1];
        float r0 = evalG(ha, C0) + evalG(hc, C0);
        float r1 = evalG(ha, C1) + evalG(hc, C1);
        r0 = red16_all(r0); r1 = red16_all(r1);
        r0 += __builtin_bit_cast(float, __builtin_amdgcn_ds_bpermute(idx16, __builtin_bit_cast(int, r0)));
        r1 += __builtin_bit_cast(float, __builtin_amdgcn_ds_bpermute(idx16, __builtin_bit_cast(int, r1)));
        r0 += __builtin_bit_cast(float, __builtin_amdgcn_ds_bpermute(idx32, __builtin_bit_cast(int, r0)));
        r1 += __builtin_bit_cast(float, __builtin_amdgcn_ds_bpermute(idx32, __builtin_bit_cast(int, r1)));
        const float x0 = r0, x1 = r1;

        // ---- gate matvec on the MFMA pipe: 4 independent depth-4 chains ----
        float ga[4];
        #pragma unroll
        for (int rt = 0; rt < 4; ++rt) {
            f32x4 a = {0.0f, 0.0f, 0.0f, 0.0f};
            a = __builtin_amdgcn_mfma_f32_16x16x32_f16(af0, wf[rt][0], a, 0, 0, 0);
            a = __builtin_amdgcn_mfma_f32_16x16x32_f16(af1, wf[rt][1], a, 0, 0, 0);
            a = __builtin_amdgcn_mfma_f32_16x16x32_f16(af2, wf[rt][2], a, 0, 0, 0);
            a = __builtin_amdgcn_mfma_f32_16x16x32_f16(af3, wf[rt][3], a, 0, 0, 0);
            ga[rt] = a[0];
        }

        const float gi = ga[0] + fmaf(x0, wi0_[0], fmaf(x1, wi1_[0], bb_[0]));
        const float gf = ga[1] + fmaf(x0, wi0_[1], fmaf(x1, wi1_[1], bb_[1]));
        const float gg = ga[2] + fmaf(x0, wi0_[2], fmaf(x1, wi1_[2], bb_[2]));
        const float go = ga[3] + fmaf(x0, wi0_[3], fmaf(x1, wi1_[3], bb_[3]));

        const float si = __builtin_amdgcn_rcpf(1.0f + __builtin_amdgcn_exp2f(-L2E * gi));
        const float sf = __builtin_amdgcn_rcpf(1.0f + __builtin_amdgcn_exp2f(-L2E * gf));
        const float so = __builtin_amdgcn_rcpf(1.0f + __builtin_amdgcn_exp2f(-L2E * go));
        const float tg = 1.0f - 2.0f * __builtin_amdgcn_rcpf(
            __builtin_amdgcn_exp2f(2.0f * L2E * gg) + 1.0f);
        c_reg = fmaf(sf, c_reg, si * tg);
        const float tc2 = 1.0f - 2.0f * __builtin_amdgcn_rcpf(
            __builtin_amdgcn_exp2f(2.0f * L2E * c_reg) + 1.0f);
        h_reg = so * tc2;

        // Tail: one f16 LDS write (+ fire-and-forget global store).
        if (grp == 0) {
            hist16[ws * ND + gl] = (_Float16)h_reg;
            out[(size_t)step * (NB * ND) + b * ND + gl] = h_reg;  // async
        }

        // LDS-only drain + raw barrier: global stores stay in flight.
        asm volatile("s_waitcnt lgkmcnt(0)" ::: "memory");
        __builtin_amdgcn_s_barrier();
    }
}

extern "C" void kernel_launch(void* const* d_in, const int* in_sizes, int n_in,
                              void* d_out, int out_size, void* d_ws, size_t ws_size,
                              hipStream_t stream) {
    const float* enc = (const float*)d_in[0];
    const float* W1w = (const float*)d_in[1];
    const float* W1b = (const float*)d_in[2];
    const float* W2w = (const float*)d_in[3];
    const float* W2b = (const float*)d_in[4];
    const float* Wih = (const float*)d_in[5];
    const float* Whh = (const float*)d_in[6];
    const float* bih = (const float*)d_in[7];
    const float* bhh = (const float*)d_in[8];
    attn_lstm_decoder<<<NB, NT, 0, stream>>>(enc, W1w, W1b, W2w, W2b,
                                             Wih, Whh, bih, bhh, (float*)d_out);
}

// Round 6
// 271.110 us; speedup vs baseline: 1.1512x; 1.1512x over previous
//
#include <hip/hip_runtime.h>

#define NB 256   // batch
#define NS 256   // seq len == number of steps
#define NE 2     // encoder dim
#define ND 128   // decoder dim
#define NT 256   // threads per block (4 waves, 1 per SIMD)
#define NN 16    // Chebyshev nodes/degree for the h -> context map

typedef float vf4 __attribute__((ext_vector_type(4)));
typedef _Float16 f16x8 __attribute__((ext_vector_type(8)));
typedef float f32x4 __attribute__((ext_vector_type(4)));

constexpr float L2E = 1.4426950408889634f;  // log2(e)
constexpr float PI_F = 3.14159265358979323846f;

// Monomial coefficients of Chebyshev T_k: T_k(h) = sum_m CT[k][m] h^m (exact ints).
__device__ const float CT[16][16] = {
 {1,0,0,0,0,0,0,0,0,0,0,0,0,0,0,0},
 {0,1,0,0,0,0,0,0,0,0,0,0,0,0,0,0},
 {-1,0,2,0,0,0,0,0,0,0,0,0,0,0,0,0},
 {0,-3,0,4,0,0,0,0,0,0,0,0,0,0,0,0},
 {1,0,-8,0,8,0,0,0,0,0,0,0,0,0,0,0},
 {0,5,0,-20,0,16,0,0,0,0,0,0,0,0,0,0},
 {-1,0,18,0,-48,0,32,0,0,0,0,0,0,0,0,0},
 {0,-7,0,56,0,-112,0,64,0,0,0,0,0,0,0,0},
 {1,0,-32,0,160,0,-256,0,128,0,0,0,0,0,0,0},
 {0,9,0,-120,0,432,0,-576,0,256,0,0,0,0,0},
 {-1,0,50,0,-400,0,1120,0,-1280,0,512,0,0,0,0,0},
 {0,-11,0,220,0,-1232,0,2816,0,-2816,0,1024,0,0,0,0},
 {1,0,-72,0,840,0,-3584,0,6912,0,-6144,0,2048,0,0,0},
 {0,13,0,-364,0,2912,0,-9984,0,16640,0,-13312,0,4096,0,0},
 {-1,0,98,0,-1568,0,9408,0,-26880,0,39424,0,-28672,0,8192,0},
 {0,-15,0,560,0,-6048,0,28800,0,-70400,0,92160,0,-61440,0,16384}};

// DPP add: x + dpp_move(x). All-VALU cross-lane (no LDS pipe, no lgkmcnt).
template <int C>
__device__ __forceinline__ float dppadd(float x) {
    return x + __builtin_bit_cast(float,
        __builtin_amdgcn_update_dpp(0, __builtin_bit_cast(int, x), C, 0xF, 0xF, true));
}
__device__ __forceinline__ float red_quad(float x) {      // sum over each quad
    x = dppadd<0xB1>(x); x = dppadd<0x4E>(x); return x;
}
__device__ __forceinline__ float red_wave64(float x) {    // valid in lane 63
    x = dppadd<0xB1>(x); x = dppadd<0x4E>(x); x = dppadd<0x141>(x);
    x = dppadd<0x140>(x); x = dppadd<0x142>(x); x = dppadd<0x143>(x); return x;
}
// All-lane 16-sum via mirror stages (each is a permutation => valid everywhere).
__device__ __forceinline__ float red16_all(float x) {
    x = dppadd<0xB1>(x);   // xor1 (quad perm)
    x = dppadd<0x4E>(x);   // xor2 (quad perm)
    x = dppadd<0x141>(x);  // row half mirror
    x = dppadd<0x140>(x);  // row mirror
    return x;
}

// One block per batch element; 256-step recurrence in-block, ONE barrier/step.
// NT=256 (4 waves, 1/SIMD): MFMA pipe time per SIMD is invariant in wave
// count (128 MFMA/block, structural), but VALU redundancy is NOT -- with 256
// threads for 128 channels each channel has only 2 copies (was 4), halving
// per-SIMD VALU issue. Wave w owns 32 channels: 8 row-tiles (4 gates x 2
// 16-blocks) x 4 k-tiles = 32 MFMA/wave. Thread (grp,nib): sub=grp&1 picks
// its 16-block, cpy=grp>>1 is the redundancy copy, used to split the
// context-poly into even/odd halves (G = E(h^2) + h*O(h^2)). All 4 gates of
// this thread's channel are lane-local in the MFMA output (all C rows
// identical; col = lane&15); one cndmask on sub selects the 16-block.
// x(k) is writer-side (round-3 proven): poly at own f32 h + red_wave64 +
// xwbuf; head does one broadcast LDS read + red_quad over 4 wave partials.
__global__ __launch_bounds__(NT, 1)
void attn_lstm_decoder(const float* __restrict__ enc,   // [B,S,E]
                       const float* __restrict__ W1w,   // [S,S]
                       const float* __restrict__ W1b,   // [S]
                       const float* __restrict__ W2w,   // [S,2S]
                       const float* __restrict__ W2b,   // [S]
                       const float* __restrict__ Wih,   // [4D,E]
                       const float* __restrict__ Whh,   // [4D,D]
                       const float* __restrict__ bih,   // [4D]
                       const float* __restrict__ bhh,   // [4D]
                       float* __restrict__ out)         // [S,B,D]
{
    const int b    = blockIdx.x;
    const int t    = threadIdx.x;
    const int wave = t >> 6;          // 0..3
    const int lane = t & 63;
    const int grp  = lane >> 4;       // 0..3: MFMA k-group
    const int nib  = lane & 15;       // MFMA n-index
    const int sub  = grp & 1;         // which 16-block of the wave's 32 ch
    const int cpy  = grp >> 1;        // redundancy copy / poly parity
    const int gl   = 32 * wave + 16 * sub + nib;   // this thread's channel

    __shared__ __align__(16) _Float16 hist16[2 * ND];   // f16 h double buffer
    __shared__ __align__(16) float xwbuf[2][8];         // 4 waves x float2
    __shared__ float A2_l[NS];
    __shared__ float g2_l[NS];
    __shared__ float e0_l[NS];
    __shared__ float e1_l[NS];
    __shared__ float Ml[NN * NN];
    __shared__ float2 Pn[NN];
    __shared__ float2 Vl[NN];
    __shared__ float Pm0[NN], Pm1[NN];

    // ---------------- setup (once per block) ----------------
    #pragma unroll
    for (int i = t; i < NS * NE; i += NT) {
        float v = enc[b * (NS * NE) + i];      // coalesced
        if (i & 1) e1_l[i >> 1] = v; else e0_l[i >> 1] = v;
    }
    {   // t covers exactly NN*NN = 256
        const int mi = t >> 4, mj = t & 15;
        const float w = (mi == 0) ? (1.0f / NN) : (2.0f / NN);
        Ml[t] = w * __cosf((float)(mi * (2 * mj + 1)) * (PI_F / (2 * NN)));
    }
    __syncthreads();

    // w1sum rows and w2term rows: 64 rows per wave (DPP reductions).
    for (int r = 0; r < 64; ++r) {
        const int s = wave * 64 + r;
        float p = W1w[s * NS + lane]       + W1w[s * NS + lane + 64]
                + W1w[s * NS + lane + 128] + W1w[s * NS + lane + 192];
        p = red_wave64(p);
        if (lane == 63) g2_l[s] = p * (2.0f * L2E);
        float qq = 0.0f;
        #pragma unroll
        for (int kk = 0; kk < 8; ++kk) {
            const int c = lane + kk * 64;
            const float ev = (c & 1) ? e1_l[c >> 1] : e0_l[c >> 1];
            qq = fmaf(ev, W2w[s * (2 * NS) + c], qq);
        }
        qq = red_wave64(qq);
        if (lane == 63) A2_l[s] = (qq + W2b[s] + W1b[s]) * (2.0f * L2E);
    }
    __syncthreads();

    // One-time node softmax: F(y_j), one node per 16-lane group (16 total).
    {
        const int jn = 4 * wave + grp;
        const float y  = __cosf((float)(2 * jn + 1) * (PI_F / (2 * NN)));
        const float C2 = -2.0f * L2E;
        float l = 0.0f, p0 = 0.0f, p1 = 0.0f;
        #pragma unroll
        for (int k = 0; k < 16; ++k) {
            const int s = k * 16 + nib;
            const float m1 = fmaf(y, g2_l[s], A2_l[s]);
            const float u  = __builtin_amdgcn_exp2f(m1);
            const float rc = __builtin_amdgcn_rcpf(u + 1.0f);
            const float e  = __builtin_amdgcn_exp2f(rc * C2);
            l += e;
            p0 = fmaf(e, e0_l[s], p0);
            p1 = fmaf(e, e1_l[s], p1);
        }
        l = red16_all(l); p0 = red16_all(p0); p1 = red16_all(p1);
        if (nib == 0) {
            const float rl = __builtin_amdgcn_rcpf(l);
            Pn[jn] = make_float2(p0 * rl, p1 * rl);
        }
    }
    __syncthreads();

    // DCT collapse: V[i] = sum_j M[i][j]*Pn[j], 1/ND folded in.
    if (t < NN) {
        float v0 = 0.0f, v1 = 0.0f;
        #pragma unroll
        for (int j = 0; j < NN; ++j) {
            v0 = fmaf(Ml[t * NN + j], Pn[j].x, v0);
            v1 = fmaf(Ml[t * NN + j], Pn[j].y, v1);
        }
        Vl[t] = make_float2(v0 * (1.0f / ND), v1 * (1.0f / ND));
    }

    // W_hh MFMA B-fragments, WAVE-LOCAL rows: tile (j,s) covers gate-j rows
    // 128*j + 32*wave + 16*s + [0,16). Lane holds B[k][n]: n = nib,
    // k = 32*kt + 8*grp + e (contiguous 8, packed little-endian).
    f16x8 wf[4][2][4];
    #pragma unroll
    for (int j = 0; j < 4; ++j) {
        #pragma unroll
        for (int s = 0; s < 2; ++s) {
            const int row = 128 * j + 32 * wave + 16 * s + nib;
            #pragma unroll
            for (int kt = 0; kt < 4; ++kt) {
                const vf4 wa = *reinterpret_cast<const vf4*>(Whh + row * ND + 32 * kt + 8 * grp);
                const vf4 wb = *reinterpret_cast<const vf4*>(Whh + row * ND + 32 * kt + 8 * grp + 4);
                f16x8 wv;
                wv[0] = (_Float16)wa.x; wv[1] = (_Float16)wa.y;
                wv[2] = (_Float16)wa.z; wv[3] = (_Float16)wa.w;
                wv[4] = (_Float16)wb.x; wv[5] = (_Float16)wb.y;
                wv[6] = (_Float16)wb.z; wv[7] = (_Float16)wb.w;
                wf[j][s][kt] = wv;
            }
        }
    }
    // All-4-gate per-lane constants for this thread's channel gl.
    float wi0_[4], wi1_[4], bb_[4];
    #pragma unroll
    for (int j = 0; j < 4; ++j) {
        const int r = 128 * j + gl;
        wi0_[j] = Wih[r * 2 + 0];
        wi1_[j] = Wih[r * 2 + 1];
        bb_[j]  = bih[r] + bhh[r];
    }

    // zero-init both h buffers
    if (t < 2 * ND) hist16[t] = (_Float16)0.0f;
    float h_reg = 0.0f, c_reg = 0.0f;
    __syncthreads();                   // Vl visible

    // Chebyshev -> monomial: Pm[m] = sum_k V[k] * CT[k][m].
    if (t < NN) {
        float s0 = 0.0f, s1 = 0.0f;
        #pragma unroll
        for (int k = 0; k < NN; ++k) {
            s0 = fmaf(Vl[k].x, CT[k][t], s0);
            s1 = fmaf(Vl[k].y, CT[k][t], s1);
        }
        Pm0[t] = s0; Pm1[t] = s1;
    }
    __syncthreads();                   // Pm visible

    // cpy-split coefficients: cpy=0 -> even monomials, cpy=1 -> odd.
    float cc0[8], cc1[8];
    #pragma unroll
    for (int i = 0; i < 8; ++i) {
        cc0[i] = Pm0[2 * i + cpy];
        cc1[i] = Pm1[2 * i + cpy];
    }

    // phaseG: this thread's half (parity cpy) of G(h) at its own f32 h;
    // wave sum over 64 lanes (32 ch x 2 parities) = the wave's x partial.
    auto phaseG = [&](float h, int pw) {
        const float h2 = h * h;
        float v0 = cc0[7], v1 = cc1[7];
        #pragma unroll
        for (int k = 6; k >= 0; --k) {
            v0 = fmaf(v0, h2, cc0[k]);
            v1 = fmaf(v1, h2, cc1[k]);
        }
        const float hsel = cpy ? h : 1.0f;
        v0 *= hsel;
        v1 *= hsel;
        v0 = red_wave64(v0); v1 = red_wave64(v1);
        if (lane == 63) {
            xwbuf[pw][2 * wave + 0] = v0;
            xwbuf[pw][2 * wave + 1] = v1;
        }
    };

    phaseG(0.0f, 0);       // x for step 0 (h = 0)
    __syncthreads();

    // ---------------- the recurrence (ONE barrier per step) ----------------
    for (int step = 0; step < NS; ++step) {
        const int pr = step & 1;
        const int rs = pr ^ 1;            // buffer holding h(step-1)
        const int ws = pr;                // buffer for h(step)
        const _Float16* hb = &hist16[rs * ND];

        // A fragments: each 16-lane group reads the SAME 16B of h (broadcast),
        // so A[m][k] = h[k] for every m; all C rows are identical.
        const f16x8 af0 = __builtin_bit_cast(f16x8, *reinterpret_cast<const int4*>(hb + 0  + 8 * grp));
        const f16x8 af1 = __builtin_bit_cast(f16x8, *reinterpret_cast<const int4*>(hb + 32 + 8 * grp));
        const f16x8 af2 = __builtin_bit_cast(f16x8, *reinterpret_cast<const int4*>(hb + 64 + 8 * grp));
        const f16x8 af3 = __builtin_bit_cast(f16x8, *reinterpret_cast<const int4*>(hb + 96 + 8 * grp));

        // x from the 4 wave partials (broadcast read + quad reduce).
        float2 xv = *reinterpret_cast<const float2*>(&xwbuf[pr][2 * (lane & 3)]);
        const float x0 = red_quad(xv.x);
        const float x1 = red_quad(xv.y);
        float bt[4];
        #pragma unroll
        for (int j = 0; j < 4; ++j)
            bt[j] = fmaf(x0, wi0_[j], fmaf(x1, wi1_[j], bb_[j]));

        // Gate matvec on the MFMA pipe: 8 independent depth-4 chains
        // (4 gates x 2 16-blocks); cndmask on sub picks this lane's block.
        float ga[4];
        #pragma unroll
        for (int j = 0; j < 4; ++j) {
            f32x4 a0 = {0.0f, 0.0f, 0.0f, 0.0f};
            f32x4 a1 = {0.0f, 0.0f, 0.0f, 0.0f};
            a0 = __builtin_amdgcn_mfma_f32_16x16x32_f16(af0, wf[j][0][0], a0, 0, 0, 0);
            a1 = __builtin_amdgcn_mfma_f32_16x16x32_f16(af0, wf[j][1][0], a1, 0, 0, 0);
            a0 = __builtin_amdgcn_mfma_f32_16x16x32_f16(af1, wf[j][0][1], a0, 0, 0, 0);
            a1 = __builtin_amdgcn_mfma_f32_16x16x32_f16(af1, wf[j][1][1], a1, 0, 0, 0);
            a0 = __builtin_amdgcn_mfma_f32_16x16x32_f16(af2, wf[j][0][2], a0, 0, 0, 0);
            a1 = __builtin_amdgcn_mfma_f32_16x16x32_f16(af2, wf[j][1][2], a1, 0, 0, 0);
            a0 = __builtin_amdgcn_mfma_f32_16x16x32_f16(af3, wf[j][0][3], a0, 0, 0, 0);
            a1 = __builtin_amdgcn_mfma_f32_16x16x32_f16(af3, wf[j][1][3], a1, 0, 0, 0);
            ga[j] = sub ? a1[0] : a0[0];
        }

        const float gi = ga[0] + bt[0];
        const float gf = ga[1] + bt[1];
        const float gg = ga[2] + bt[2];
        const float go = ga[3] + bt[3];

        const float si = __builtin_amdgcn_rcpf(1.0f + __builtin_amdgcn_exp2f(-L2E * gi));
        const float sf = __builtin_amdgcn_rcpf(1.0f + __builtin_amdgcn_exp2f(-L2E * gf));
        const float so = __builtin_amdgcn_rcpf(1.0f + __builtin_amdgcn_exp2f(-L2E * go));
        const float tg = 1.0f - 2.0f * __builtin_amdgcn_rcpf(
            __builtin_amdgcn_exp2f(2.0f * L2E * gg) + 1.0f);
        c_reg = fmaf(sf, c_reg, si * tg);
        const float tc2 = 1.0f - 2.0f * __builtin_amdgcn_rcpf(
            __builtin_amdgcn_exp2f(2.0f * L2E * c_reg) + 1.0f);
        h_reg = so * tc2;

        // Tail: one f16 LDS write per channel (+ fire-and-forget global).
        if (cpy == 0) {
            hist16[ws * ND + gl] = (_Float16)h_reg;
            out[(size_t)step * (NB * ND) + b * ND + gl] = h_reg;  // async
        }
        phaseG(h_reg, pr ^ 1);                            // x for step k+1

        // LDS-only drain + raw barrier: global stores stay in flight.
        asm volatile("s_waitcnt lgkmcnt(0)" ::: "memory");
        __builtin_amdgcn_s_barrier();
    }
}

extern "C" void kernel_launch(void* const* d_in, const int* in_sizes, int n_in,
                              void* d_out, int out_size, void* d_ws, size_t ws_size,
                              hipStream_t stream) {
    const float* enc = (const float*)d_in[0];
    const float* W1w = (const float*)d_in[1];
    const float* W1b = (const float*)d_in[2];
    const float* W2w = (const float*)d_in[3];
    const float* W2b = (const float*)d_in[4];
    const float* Wih = (const float*)d_in[5];
    const float* Whh = (const float*)d_in[6];
    const float* bih = (const float*)d_in[7];
    const float* bhh = (const float*)d_in[8];
    attn_lstm_decoder<<<NB, NT, 0, stream>>>(enc, W1w, W1b, W2w, W2b,
                                             Wih, Whh, bih, bhh, (float*)d_out);
}